// Round 9
// baseline (224.161 us; speedup 1.0000x reference)
//
#include <hip/hip_runtime.h>
#include <hip/hip_bf16.h>

#define BB   256
#define NIN  1152
#define OO   10
#define IL   8
#define OL   16
#define ROW  (OO*OL)      // 160
#define EPSQ 1e-7f
#define NCH  36           // n-chunks (partial buffers)

typedef short s16x8 __attribute__((ext_vector_type(8)));
typedef float f32x4 __attribute__((ext_vector_type(4)));

__device__ __forceinline__ unsigned short f2bf(float f) {
    unsigned u = __builtin_bit_cast(unsigned, f);
    u += 0x7FFFu + ((u >> 16) & 1u);   // RNE
    return (unsigned short)(u >> 16);
}

// Pack w[n][o][i][k] (fp32) -> wp[(n*10+o)*16 + l][e=i] (bf16), i.e. B-fragment
// order: lane l (=output col k within o) holds the 8 contraction values w[:,l].
__global__ __launch_bounds__(256) void prep_w(const float* __restrict__ w,
                                              short* __restrict__ wp)
{
    const int id = blockIdx.x * 256 + threadIdx.x;   // < 1152*10*16
    const int l  = id & 15;
    const int no = id >> 4;                          // n*10+o
    const float* src = w + (size_t)no * (IL * OL) + l;
    union { s16x8 v; unsigned short h[8]; } pk;
    #pragma unroll
    for (int i = 0; i < IL; ++i)
        pk.h[i] = f2bf(src[i * OL]);
    *reinterpret_cast<s16x8*>(wp + (size_t)id * 8) = pk.v;
}

// Pack x[b][n][0..7] (fp32) -> xp[n*256 + b][e=i] (bf16): A-fragment order.
// Thread id = b*1152+n so the fp32 reads are fully coalesced.
__global__ __launch_bounds__(256) void prep_x(const float* __restrict__ x,
                                              short* __restrict__ xp)
{
    const int id = blockIdx.x * 256 + threadIdx.x;   // < 256*1152
    const int n  = id % NIN;
    const int b  = id / NIN;
    const float4* src = reinterpret_cast<const float4*>(x + (size_t)id * IL);
    const float4 a = src[0], c = src[1];
    union { s16x8 v; unsigned short h[8]; } pk;
    pk.h[0] = f2bf(a.x); pk.h[1] = f2bf(a.y); pk.h[2] = f2bf(a.z); pk.h[3] = f2bf(a.w);
    pk.h[4] = f2bf(c.x); pk.h[5] = f2bf(c.y); pk.h[6] = f2bf(c.z); pk.h[7] = f2bf(c.w);
    *reinterpret_cast<s16x8*>(xp + ((size_t)n * BB + b) * 8) = pk.v;
}

// One routing pass, u_hat recomputed via MFMA (never materialized).
// Grid (16 b-tiles, 36 n-chunks), 256 thr = 4 waves; wave wv owns the block's
// 16-b tile for n = nc*32 + wv*8 + 0..7. Per n: A = x-frag (lanes 0-15 hold
// the 8 real k-slots, others zero), B[o] = w-frag; acc[o] = mfma(A,B[o],0)
// gives U in C-layout: col k = lane&15, row b = (lane>>4)*4+reg (verified
// layout). Routing epilogue stays in that layout: dot over k = width-16
// butterfly; softmax over o in-lane; sp[o] += c*acc[o] persists across n.
// 4-wave LDS reduce -> fp32 partial[nc][b][160].
template<int ITER>
__global__ __launch_bounds__(256) void caps_pass(
    const short* __restrict__ xp, const short* __restrict__ wp,
    const float* __restrict__ vin, float* __restrict__ partial)
{
    __shared__ float red[256 * 41];
    const int t  = threadIdx.x;
    const int l  = t & 63;
    const int wv = t >> 6;
    const int b0 = blockIdx.x * 16;
    const int nc = blockIdx.y;
    const int l15 = l & 15, lq = l >> 4;
    const bool lo = (l < 16);

    f32x4 sp[OO];
    #pragma unroll
    for (int o = 0; o < OO; ++o) sp[o] = (f32x4){0.f, 0.f, 0.f, 0.f};

    float vreg[4][OO];
    if (ITER) {
        #pragma unroll
        for (int r = 0; r < 4; ++r)
            #pragma unroll
            for (int o = 0; o < OO; ++o)
                vreg[r][o] = vin[(size_t)(b0 + lq * 4 + r) * ROW + o * OL + l15];
    }

    const s16x8 zfrag = (s16x8){0, 0, 0, 0, 0, 0, 0, 0};

    for (int nn = 0; nn < 8; ++nn) {
        const int n = nc * 32 + wv * 8 + nn;
        const s16x8 A = lo
            ? *reinterpret_cast<const s16x8*>(xp + ((size_t)n * BB + b0 + l) * 8)
            : zfrag;

        f32x4 acc[OO];
        #pragma unroll
        for (int o = 0; o < OO; ++o) {
            const s16x8 Bo = lo
                ? *reinterpret_cast<const s16x8*>(wp + (((size_t)n * OO + o) * 16 + l) * 8)
                : zfrag;
            acc[o] = __builtin_amdgcn_mfma_f32_16x16x32_bf16(
                A, Bo, (f32x4){0.f, 0.f, 0.f, 0.f}, 0, 0, 0);
        }

        if (ITER == 0) {
            #pragma unroll
            for (int o = 0; o < OO; ++o) sp[o] += acc[o];
        } else {
            #pragma unroll
            for (int r = 0; r < 4; ++r) {
                float d[OO];
                #pragma unroll
                for (int o = 0; o < OO; ++o) {
                    float td = acc[o][r] * vreg[r][o];
                    td += __shfl_xor(td, 1, 16);
                    td += __shfl_xor(td, 2, 16);
                    td += __shfl_xor(td, 4, 16);
                    td += __shfl_xor(td, 8, 16);
                    d[o] = td;
                }
                float mx = d[0];
                #pragma unroll
                for (int o = 1; o < OO; ++o) mx = fmaxf(mx, d[o]);
                float e[OO], se = 0.f;
                #pragma unroll
                for (int o = 0; o < OO; ++o) { e[o] = __expf(d[o] - mx); se += e[o]; }
                const float rinv = 1.f / se;
                #pragma unroll
                for (int o = 0; o < OO; ++o)
                    sp[o][r] = fmaf(e[o] * rinv, acc[o][r], sp[o][r]);
            }
        }
    }

    // cross-wave reduce (stride 41 dwords -> conflict-free)
    #pragma unroll
    for (int j = 0; j < 40; ++j)
        red[t * 41 + j] = sp[j >> 2][j & 3];
    __syncthreads();

    #pragma unroll
    for (int jj = 0; jj < 10; ++jj) {
        const int j = wv * 10 + jj;
        const int o = j >> 2, r = j & 3;
        const float s = red[(0 * 64 + l) * 41 + j] + red[(1 * 64 + l) * 41 + j]
                      + red[(2 * 64 + l) * 41 + j] + red[(3 * 64 + l) * 41 + j];
        partial[((size_t)nc * BB + b0 + lq * 4 + r) * ROW + o * OL + l15] = s;
    }
}

// Sum partials over chunks + bias, squash; optional prevAdd (running v-sum).
__global__ __launch_bounds__(192) void caps_reduce(
    const float* __restrict__ partial, const float* __restrict__ bias,
    const float* __restrict__ prevAdd, float* __restrict__ outv, float scale)
{
    const int t = threadIdx.x;
    if (t >= ROW) return;
    const int b = blockIdx.x;

    float s0 = 0.f, s1 = 0.f, s2 = 0.f, s3 = 0.f;
    const float* p = partial + (size_t)b * ROW + t;
    #pragma unroll
    for (int ch = 0; ch < NCH; ch += 4) {
        s0 += p[(size_t)(ch + 0) * BB * ROW];
        s1 += p[(size_t)(ch + 1) * BB * ROW];
        s2 += p[(size_t)(ch + 2) * BB * ROW];
        s3 += p[(size_t)(ch + 3) * BB * ROW];
    }
    float s = scale * ((s0 + s1) + (s2 + s3)) + bias[t];

    float d = s * s;
    d += __shfl_xor(d, 1, 16);
    d += __shfl_xor(d, 2, 16);
    d += __shfl_xor(d, 4, 16);
    d += __shfl_xor(d, 8, 16);
    const float f = d / ((1.f + d) * sqrtf(d + EPSQ));
    float v = f * s;
    if (prevAdd) v += prevAdd[(size_t)b * ROW + t];
    outv[(size_t)b * ROW + t] = v;
}

extern "C" void kernel_launch(void* const* d_in, const int* in_sizes, int n_in,
                              void* d_out, int out_size, void* d_ws, size_t ws_size,
                              hipStream_t stream) {
    const float* x    = (const float*)d_in[0]; // (B, NIN, 8, 1)
    const float* w    = (const float*)d_in[1]; // (1, NIN, O, 8, 16)
    const float* bias = (const float*)d_in[2]; // (1, 1, O, 16, 1)
    float* out = (float*)d_out;                // (B, 1, O, 16, 1)

    short* xp = (short*)d_ws;                               // 1152*256*8 bf16
    short* wp = xp + (size_t)NIN * BB * 8;                  // 1152*10*16*8 bf16
    float* partial = (float*)(wp + (size_t)NIN * OO * 16 * 8); // 36*256*160 f32
    float* v0  = partial + (size_t)NCH * BB * ROW;
    float* vsb = v0 + (size_t)BB * ROW;

    prep_w<<<(NIN * OO * 16) / 256, 256, 0, stream>>>(w, wp);
    prep_x<<<(BB * NIN) / 256, 256, 0, stream>>>(x, xp);

    const dim3 pg(BB / 16, NCH);
    // iter0: uniform c (scale 0.1) -> v0
    caps_pass<0><<<pg, 256, 0, stream>>>(xp, wp, nullptr, partial);
    caps_reduce<<<BB, 192, 0, stream>>>(partial, bias, nullptr, v0, 0.1f);
    // iter1: c = softmax(u.v0) -> vsb = v0 + v1
    caps_pass<1><<<pg, 256, 0, stream>>>(xp, wp, v0, partial);
    caps_reduce<<<BB, 192, 0, stream>>>(partial, bias, v0, vsb, 1.0f);
    // iter2: c = softmax(u.(v0+v1)) -> out
    caps_pass<2><<<pg, 256, 0, stream>>>(xp, wp, vsb, partial);
    caps_reduce<<<BB, 192, 0, stream>>>(partial, bias, nullptr, out, 1.0f);
}

// Round 10
// 173.679 us; speedup vs baseline: 1.2907x; 1.2907x over previous
//
#include <hip/hip_runtime.h>

#define BB    256
#define NIN   1152
#define OO    10
#define IL    8
#define OL    16
#define ROW   160
#define EPSQ  1e-7f
#define NCH   144
#define NPN   8      // n per chunk
#define BTILE 64

// One routing pass; u_hat recomputed on the fly (never materialized).
// Grid (BB/64, 144). Block 256 thr = 64 groups of 4 lanes; group g owns
// b = b0+g for the chunk's 8 n's. Lane q owns row-chunks c = q+4j (8 floats
// each, c*8.. of the 160-float [o][k] row; o = c>>1, halve h = c&1).
// w chunk (8 n x 5 KB = 40 KB) staged in LDS once per block; compute reads
// are same-address across the wave's 16 groups -> HW broadcast, and the 4
// distinct q-streams land 2-way on banks (free). Epilogue = round-8's
// verified 4-lane softmax (dot + shfl_xor(1)/(2) over width 4).
template<int ITER>
__global__ __launch_bounds__(256) void caps_pass(
    const float* __restrict__ x, const float* __restrict__ w,
    const float* __restrict__ vin, float* __restrict__ partial)
{
    __shared__ float wls[NPN * 1280];   // 40 KB
    __shared__ float xls[BTILE][68];    // 64 data + 4 pad (bank spread)
    const int t  = threadIdx.x;
    const int q  = t & 3;
    const int g  = t >> 2;              // 0..63 = b within tile
    const int b0 = blockIdx.x * BTILE;
    const int nc = blockIdx.y;
    const int n0 = nc * NPN;

    // stage w slice [n0..n0+7] (8*1280 contiguous floats), coalesced
    {
        const float4* wg = reinterpret_cast<const float4*>(w + (size_t)n0 * 1280);
        float4* wd = reinterpret_cast<float4*>(wls);
        #pragma unroll
        for (int j = 0; j < 10; ++j)
            wd[t + j * 256] = wg[t + j * 256];
    }
    // stage x tile [b0..][n0..n0+7][8]: 64 consecutive floats per b
    {
        const float4* xg = reinterpret_cast<const float4*>(x);
        #pragma unroll
        for (int j = 0; j < 4; ++j) {
            const int id = t + j * 256;   // 0..1023
            const int b  = id >> 4;
            const int r  = id & 15;
            *reinterpret_cast<float4*>(&xls[b][r * 4]) =
                xg[((size_t)(b0 + b) * NIN + n0) * 2 + r];
        }
    }

    int bj[5];
    #pragma unroll
    for (int j = 0; j < 5; ++j) {
        const int c = q + 4 * j;
        bj[j] = (c >> 1) * 128 + (c & 1) * 8;   // o*128 + h*8
    }

    float vs[5][8];
    if (ITER) {
        #pragma unroll
        for (int j = 0; j < 5; ++j) {
            const float* vp = vin + (size_t)(b0 + g) * ROW + (q + 4 * j) * 8;
            const float4 a = *reinterpret_cast<const float4*>(vp);
            const float4 c4 = *reinterpret_cast<const float4*>(vp + 4);
            vs[j][0] = a.x;  vs[j][1] = a.y;  vs[j][2] = a.z;  vs[j][3] = a.w;
            vs[j][4] = c4.x; vs[j][5] = c4.y; vs[j][6] = c4.z; vs[j][7] = c4.w;
        }
    }

    float sp[5][8];
    #pragma unroll
    for (int j = 0; j < 5; ++j)
        #pragma unroll
        for (int e = 0; e < 8; ++e) sp[j][e] = 0.f;

    __syncthreads();

    for (int nn = 0; nn < NPN; ++nn) {
        float xr[8];
        #pragma unroll
        for (int h = 0; h < 2; ++h) {
            const float4 xv = *reinterpret_cast<const float4*>(&xls[g][nn * 8 + h * 4]);
            xr[h * 4 + 0] = xv.x; xr[h * 4 + 1] = xv.y;
            xr[h * 4 + 2] = xv.z; xr[h * 4 + 3] = xv.w;
        }
        const float* wn = wls + nn * 1280;

        float acc[5][8];
        #pragma unroll
        for (int j = 0; j < 5; ++j) {
            #pragma unroll
            for (int e = 0; e < 8; ++e) acc[j][e] = 0.f;
            #pragma unroll
            for (int i = 0; i < IL; ++i) {
                const float4 wlo = *reinterpret_cast<const float4*>(wn + bj[j] + i * 16);
                const float4 whi = *reinterpret_cast<const float4*>(wn + bj[j] + i * 16 + 4);
                acc[j][0] = fmaf(wlo.x, xr[i], acc[j][0]);
                acc[j][1] = fmaf(wlo.y, xr[i], acc[j][1]);
                acc[j][2] = fmaf(wlo.z, xr[i], acc[j][2]);
                acc[j][3] = fmaf(wlo.w, xr[i], acc[j][3]);
                acc[j][4] = fmaf(whi.x, xr[i], acc[j][4]);
                acc[j][5] = fmaf(whi.y, xr[i], acc[j][5]);
                acc[j][6] = fmaf(whi.z, xr[i], acc[j][6]);
                acc[j][7] = fmaf(whi.w, xr[i], acc[j][7]);
            }
        }

        if (ITER == 0) {
            #pragma unroll
            for (int j = 0; j < 5; ++j)
                #pragma unroll
                for (int e = 0; e < 8; ++e) sp[j][e] += acc[j][e];
        } else {
            float d[5], dd[5];
            #pragma unroll
            for (int j = 0; j < 5; ++j) {
                float a = acc[j][0] * vs[j][0];
                #pragma unroll
                for (int e = 1; e < 8; ++e) a = fmaf(acc[j][e], vs[j][e], a);
                a += __shfl_xor(a, 1, 4);      // combine halves -> full 16-k dot
                d[j] = a;
            }
            #pragma unroll
            for (int j = 0; j < 5; ++j) dd[j] = __shfl_xor(d[j], 2, 4);

            float mx = fmaxf(d[0], dd[0]);
            #pragma unroll
            for (int j = 1; j < 5; ++j) mx = fmaxf(mx, fmaxf(d[j], dd[j]));
            float e_[5], se = 0.f;
            #pragma unroll
            for (int j = 0; j < 5; ++j) {
                e_[j] = __expf(d[j] - mx);
                se += e_[j] + __expf(dd[j] - mx);
            }
            const float rinv = 1.f / se;
            #pragma unroll
            for (int j = 0; j < 5; ++j) {
                const float c = e_[j] * rinv;
                #pragma unroll
                for (int e = 0; e < 8; ++e)
                    sp[j][e] = fmaf(c, acc[j][e], sp[j][e]);
            }
        }
    }

    // each (b, chunk) owned by exactly one group: direct partial write
    #pragma unroll
    for (int j = 0; j < 5; ++j) {
        float* pp = partial + ((size_t)nc * BB + b0 + g) * ROW + (q + 4 * j) * 8;
        *reinterpret_cast<float4*>(pp) =
            make_float4(sp[j][0], sp[j][1], sp[j][2], sp[j][3]);
        *reinterpret_cast<float4*>(pp + 4) =
            make_float4(sp[j][4], sp[j][5], sp[j][6], sp[j][7]);
    }
}

// Sum partials over chunks + bias, squash; optional prevAdd (running v-sum).
__global__ __launch_bounds__(192) void caps_reduce(
    const float* __restrict__ partial, const float* __restrict__ bias,
    const float* __restrict__ prevAdd, float* __restrict__ outv, float scale)
{
    const int t = threadIdx.x;
    if (t >= ROW) return;
    const int b = blockIdx.x;

    float s0 = 0.f, s1 = 0.f, s2 = 0.f, s3 = 0.f;
    const float* p = partial + (size_t)b * ROW + t;
    for (int ch = 0; ch < NCH; ch += 4) {
        s0 += p[(size_t)(ch + 0) * BB * ROW];
        s1 += p[(size_t)(ch + 1) * BB * ROW];
        s2 += p[(size_t)(ch + 2) * BB * ROW];
        s3 += p[(size_t)(ch + 3) * BB * ROW];
    }
    float s = scale * ((s0 + s1) + (s2 + s3)) + bias[t];

    float d = s * s;
    d += __shfl_xor(d, 1, 16);
    d += __shfl_xor(d, 2, 16);
    d += __shfl_xor(d, 4, 16);
    d += __shfl_xor(d, 8, 16);
    const float f = d / ((1.f + d) * sqrtf(d + EPSQ));
    float v = f * s;
    if (prevAdd) v += prevAdd[(size_t)b * ROW + t];
    outv[(size_t)b * ROW + t] = v;
}

extern "C" void kernel_launch(void* const* d_in, const int* in_sizes, int n_in,
                              void* d_out, int out_size, void* d_ws, size_t ws_size,
                              hipStream_t stream) {
    const float* x    = (const float*)d_in[0]; // (B, NIN, 8, 1)
    const float* w    = (const float*)d_in[1]; // (1, NIN, O, 8, 16)
    const float* bias = (const float*)d_in[2]; // (1, 1, O, 16, 1)
    float* out = (float*)d_out;                // (B, 1, O, 16, 1)

    float* partial = (float*)d_ws;                       // 144*256*160 f32
    float* v0  = partial + (size_t)NCH * BB * ROW;
    float* vsb = v0 + (size_t)BB * ROW;

    const dim3 pg(BB / BTILE, NCH);

    // iter0: uniform c (scale 0.1) -> v0
    caps_pass<0><<<pg, 256, 0, stream>>>(x, w, nullptr, partial);
    caps_reduce<<<BB, 192, 0, stream>>>(partial, bias, nullptr, v0, 0.1f);
    // iter1: c = softmax(u.v0) -> vsb = v0 + v1
    caps_pass<1><<<pg, 256, 0, stream>>>(x, w, v0, partial);
    caps_reduce<<<BB, 192, 0, stream>>>(partial, bias, v0, vsb, 1.0f);
    // iter2: c = softmax(u.(v0+v1)) -> out
    caps_pass<2><<<pg, 256, 0, stream>>>(x, w, vsb, partial);
    caps_reduce<<<BB, 192, 0, stream>>>(partial, bias, nullptr, out, 1.0f);
}